// Round 24
// baseline (118.067 us; speedup 1.0000x reference)
//
#include <hip/hip_runtime.h>
#include <math.h>

// Problem constants (from reference setup_inputs)
static constexpr int N_ = 4, R_ = 256, C_ = 1024, H_ = 50, W_ = 50, P_ = 7;
static constexpr int HW_ = H_ * W_;            // 2500 words per plane
static constexpr int PP_ = P_ * P_;            // 49 output pixels per (roi, channel)
static constexpr int CHB_ = 4;                 // channels per block (float4-interleaved)
static constexpr int WVS_ = 8;                 // waves per block (512 threads)
static constexpr int P4_ = 2502;               // staged float4 slots; 40,032 B
static constexpr int NTASK = R_ * PP_;         // 12544 = 64 * 196 exactly
static constexpr int NIT = NTASK / 64;         // 196 wave-iterations per block
static constexpr int TBE_ = 3;                 // table entry = 3 x uint4 = 48 B

// Per-axis geometry, ABSOLUTE indices. rois >= 0 => i0 >= 0 (no left clamp).
// Zero-padding validity folded into weights; i0 clamped <= L-1.
// A-sub-sample corners span rows/cols {0,1} only (wA[2] == 0 -> pruned).
__device__ __forceinline__ void axis_w(float p0, float p1, int L,
                                       int& i0c, float wA[2], float wB[3]) {
    float f0 = floorf(p0); int i0 = (int)f0; float a0 = p0 - f0;
    float f1 = floorf(p1); int i1 = (int)f1; float a1 = p1 - f1;
    const bool o = (i1 > i0);
    wA[0] = 1.0f - a0; wA[1] = a0;
    wB[0] = o ? 0.0f : (1.0f - a1);
    wB[1] = o ? (1.0f - a1) : a1;
    wB[2] = o ? a1 : 0.0f;
    if (i0 > L - 1)     { wA[0] = 0.0f; wB[0] = 0.0f; }
    if (i0 + 1 > L - 1) { wA[1] = 0.0f; wB[1] = 0.0f; }
    if (i0 + 2 > L - 1) {               wB[2] = 0.0f; }
    i0c = min(max(i0, 0), L - 1);
}

// GEOMETRY PRE-PASS (r23): one entry per (image, task); 48 B each.
__global__ __launch_bounds__(256) void geom_kernel(
    const float* __restrict__ rois, uint* __restrict__ tab) {
    const int g = blockIdx.x * 256 + threadIdx.x;    // 0 .. 50175
    const int n  = (int)((unsigned)g / (unsigned)NTASK);
    const int t  = g - n * NTASK;
    const int ri = (int)((unsigned)t / 49u);
    const int px = t - ri * 49;
    const int pi = (int)((unsigned)px / 7u);
    const int pj = px - pi * 7;

    const float4 roi = reinterpret_cast<const float4*>(rois)[n * R_ + ri];
    const float y1 = roi.x * 0.0625f;
    const float x1 = roi.y * 0.0625f;
    const float y2 = (roi.x + roi.z) * 0.0625f;
    const float x2 = (roi.y + roi.w) * 0.0625f;
    const float sy = (y2 - y1) * (1.0f / 13.0f);
    const float sx = (x2 - x1) * (1.0f / 13.0f);

    const float py0 = y1 + sy * (float)(2 * pi);
    const float py1 = y1 + sy * (float)(2 * pi + 1);
    const float qx0 = x1 + sx * (float)(2 * pj);
    const float qx1 = x1 + sx * (float)(2 * pj + 1);

    int iy0; float wyA[2], wyB[3];
    axis_w(py0, py1, H_, iy0, wyA, wyB);
    int ix0; float wxA[2], wxB[3];
    axis_w(qx0, qx1, W_, ix0, wxA, wxB);

    const int b0 = iy0 * W_ + ix0;                   // <= 2499, fits 12 bits
    const int d1 = min(iy0 + 1, H_ - 1) - iy0;       // 0 or 1
    const int d2 = min(iy0 + 2, H_ - 1) - iy0;       // 0, 1 or 2
    const uint packed = (uint)b0 | ((uint)d1 << 12) | ((uint)d2 << 14);
    const uint oo = (uint)(ri * (C_ * PP_) + px);

    uint4* e = reinterpret_cast<uint4*>(tab) + (size_t)g * TBE_;
    e[0] = make_uint4(packed, oo, __float_as_uint(wyA[0]), __float_as_uint(wyA[1]));
    e[1] = make_uint4(__float_as_uint(wyB[0]), __float_as_uint(wyB[1]),
                      __float_as_uint(wyB[2]), __float_as_uint(wxA[0]));
    e[2] = make_uint4(__float_as_uint(wxA[1]), __float_as_uint(wxB[0]),
                      __float_as_uint(wxB[1]), __float_as_uint(wxB[2]));
}

// MAIN (r23 structure) + ONE-ITERATION TABLE PREFETCH. r23's body loads its
// table entry at the head of the iteration, AFTER the previous iteration's 4
// stores -- vmcnt retires in issue order, so the wait on the loads drains the
// stores first, chaining store-retirement latency into every iteration (the
// measured sum-plateau: DS 37us + write 33us ~ 68us envelope, no overlap).
// Prefetching iteration k+1's entry BEFORE iteration k's stores makes the
// first-use wait resolve at vmcnt(4) (the 4 newer stores) with zero drain.
__global__ __launch_bounds__(512, 8) void roipool_kernel(
    const uint* __restrict__ tab,
    const float* __restrict__ fm,
    float* __restrict__ out) {

    __shared__ float4 sh4[P4_];               // 40,032 B -> 4 blocks/CU

    const int b  = blockIdx.x;                // grid = N_ * 256
    const int n  = b >> 8;
    const int c0 = (b & 255) * CHB_;
    const int tid = threadIdx.x;
    const int lane = tid & 63;
    const int wv = __builtin_amdgcn_readfirstlane(tid >> 6);

    // ---- transpose-stage (unchanged) ----
    {
        const int gpb = (n * C_ + c0) * HW_;
        for (int p = tid; p < P4_; p += 512) {
            const int sp = min(p, HW_ - 1);
            float4 v;
            v.x = fm[gpb + sp];
            v.y = fm[gpb + HW_ + sp];
            v.z = fm[gpb + 2 * HW_ + sp];
            v.w = fm[gpb + 3 * HW_ + sp];
            sh4[p] = v;
        }
    }
    __syncthreads();

    const size_t obase = ((size_t)n * R_ * C_ + c0) * PP_;
    const uint4* __restrict__ tb =
        reinterpret_cast<const uint4*>(tab) + (size_t)(n * NTASK + lane) * TBE_;

    // Prologue: load entry for it = wv.
    size_t idx = (size_t)(wv << 6) * TBE_;
    uint4 E0 = tb[idx], E1 = tb[idx + 1], E2 = tb[idx + 2];

    for (int it = wv; it < NIT; it += WVS_) {
        // Prefetch next iteration's entry FIRST (before this iter's stores).
        const int itn = (it + WVS_ < NIT) ? (it + WVS_) : it;   // tail: reload self
        const size_t nidx = (size_t)(itn << 6) * TBE_;
        const uint4 F0 = tb[nidx], F1 = tb[nidx + 1], F2 = tb[nidx + 2];

        const int b0 = (int)(E0.x & 0xFFFu);
        const int b1 = b0 + (int)((E0.x >> 12) & 3u) * W_;
        const int b2 = b0 + (int)((E0.x >> 14) & 3u) * W_;

        const float wyA0 = __uint_as_float(E0.z), wyA1 = __uint_as_float(E0.w);
        const float wyB0 = __uint_as_float(E1.x), wyB1 = __uint_as_float(E1.y);
        const float wyB2 = __uint_as_float(E1.z);
        const float wxA0 = __uint_as_float(E1.w), wxA1 = __uint_as_float(E2.x);
        const float wxB0 = __uint_as_float(E2.y), wxB1 = __uint_as_float(E2.z);
        const float wxB2 = __uint_as_float(E2.w);

        const float4* __restrict__ B0 = sh4 + b0;
        const float4* __restrict__ B1 = sh4 + b1;
        const float4* __restrict__ B2 = sh4 + b2;

        // 9 x ds_read_b128: the 3x3 window for all 4 channels at once.
        const float4 v00 = B0[0], v01 = B0[1], v02 = B0[2];
        const float4 v10 = B1[0], v11 = B1[1], v12 = B1[2];
        const float4 v20 = B2[0], v21 = B2[1], v22 = B2[2];

        float r0, r1, r2, r3;
#define REDUCE_CH(CMP, RES) do {                                               \
        const float tA0 = fmaf(wyA1, v10.CMP, wyA0 * v00.CMP);                 \
        const float tA1 = fmaf(wyA1, v11.CMP, wyA0 * v01.CMP);                 \
        const float tA2 = fmaf(wyA1, v12.CMP, wyA0 * v02.CMP);                 \
        const float tB0 = fmaf(wyB2, v20.CMP, fmaf(wyB1, v10.CMP, wyB0 * v00.CMP)); \
        const float tB1 = fmaf(wyB2, v21.CMP, fmaf(wyB1, v11.CMP, wyB0 * v01.CMP)); \
        const float tB2 = fmaf(wyB2, v22.CMP, fmaf(wyB1, v12.CMP, wyB0 * v02.CMP)); \
        const float s00 = fmaf(wxA1, tA1, wxA0 * tA0);                         \
        const float s01 = fmaf(wxB2, tA2, fmaf(wxB1, tA1, wxB0 * tA0));        \
        const float s10 = fmaf(wxA1, tB1, wxA0 * tB0);                         \
        const float s11 = fmaf(wxB2, tB2, fmaf(wxB1, tB1, wxB0 * tB0));        \
        RES = fmaxf(fmaxf(s00, s01), fmaxf(s10, s11));                         \
    } while (0)
        REDUCE_CH(x, r0);
        REDUCE_CH(y, r1);
        REDUCE_CH(z, r2);
        REDUCE_CH(w, r3);
#undef REDUCE_CH

        float* __restrict__ po = out + obase + E0.y;
        po[0]       = r0;
        po[PP_]     = r1;
        po[2 * PP_] = r2;
        po[3 * PP_] = r3;

        // Swap in the prefetched entry (first use of F -> wait resolves at
        // vmcnt(4): only the 4 stores above are newer).
        E0 = F0; E1 = F1; E2 = F2;
    }
}

extern "C" void kernel_launch(void* const* d_in, const int* in_sizes, int n_in,
                              void* d_out, int out_size, void* d_ws, size_t ws_size,
                              hipStream_t stream) {
    const float* rois = (const float*)d_in[0];        // [4,256,4]
    const float* fm   = (const float*)d_in[1];        // [4,1024,50,50]
    float* out        = (float*)d_out;                // [4,256,1024,7,7]
    uint* tab         = (uint*)d_ws;                  // 50176 * 48 B = 2.41 MB

    geom_kernel<<<196, 256, 0, stream>>>(rois, tab);
    const int blocks = N_ * (C_ / CHB_);              // 4 * 256 = 1024
    roipool_kernel<<<blocks, 512, 0, stream>>>(tab, fm, out);
}

// Round 25
// 67.619 us; speedup vs baseline: 1.7461x; 1.7461x over previous
//
#include <hip/hip_runtime.h>
#include <math.h>

// Problem constants (from reference setup_inputs)
static constexpr int N_ = 4, R_ = 256, C_ = 1024, H_ = 50, W_ = 50, P_ = 7;
static constexpr int HW_ = H_ * W_;            // 2500 words per plane
static constexpr int PP_ = P_ * P_;            // 49 output pixels per (roi, channel)
static constexpr int CHB_ = 4;                 // channels per block (float4-interleaved)
static constexpr int WVS_ = 8;                 // waves per block (512 threads)
static constexpr int P4_ = 2502;               // staged float4 slots; 40,032 B
static constexpr int NTASK = R_ * PP_;         // 12544 = 64 * 196 exactly
static constexpr int NIT = NTASK / 64;         // 196 wave-iterations per block
static constexpr int TBE_ = 3;                 // table entry = 3 x uint4 = 48 B

// Per-axis geometry, ABSOLUTE indices. rois >= 0 => i0 >= 0 (no left clamp).
// Zero-padding validity folded into weights; i0 clamped <= L-1.
// A-sub-sample corners span rows/cols {0,1} only (wA[2] == 0 -> pruned).
__device__ __forceinline__ void axis_w(float p0, float p1, int L,
                                       int& i0c, float wA[2], float wB[3]) {
    float f0 = floorf(p0); int i0 = (int)f0; float a0 = p0 - f0;
    float f1 = floorf(p1); int i1 = (int)f1; float a1 = p1 - f1;
    const bool o = (i1 > i0);
    wA[0] = 1.0f - a0; wA[1] = a0;
    wB[0] = o ? 0.0f : (1.0f - a1);
    wB[1] = o ? (1.0f - a1) : a1;
    wB[2] = o ? a1 : 0.0f;
    if (i0 > L - 1)     { wA[0] = 0.0f; wB[0] = 0.0f; }
    if (i0 + 1 > L - 1) { wA[1] = 0.0f; wB[1] = 0.0f; }
    if (i0 + 2 > L - 1) {               wB[2] = 0.0f; }
    i0c = min(max(i0, 0), L - 1);
}

// GEOMETRY PRE-PASS: one entry per (image, task); 48 B each. All 256
// channel-group blocks of an image share this geometry (was 256x redundant).
__global__ __launch_bounds__(256) void geom_kernel(
    const float* __restrict__ rois, uint* __restrict__ tab) {
    const int g = blockIdx.x * 256 + threadIdx.x;    // 0 .. 50175
    const int n  = (int)((unsigned)g / (unsigned)NTASK);
    const int t  = g - n * NTASK;
    const int ri = (int)((unsigned)t / 49u);
    const int px = t - ri * 49;
    const int pi = (int)((unsigned)px / 7u);
    const int pj = px - pi * 7;

    const float4 roi = reinterpret_cast<const float4*>(rois)[n * R_ + ri];
    const float y1 = roi.x * 0.0625f;
    const float x1 = roi.y * 0.0625f;
    const float y2 = (roi.x + roi.z) * 0.0625f;
    const float x2 = (roi.y + roi.w) * 0.0625f;
    const float sy = (y2 - y1) * (1.0f / 13.0f);
    const float sx = (x2 - x1) * (1.0f / 13.0f);

    const float py0 = y1 + sy * (float)(2 * pi);
    const float py1 = y1 + sy * (float)(2 * pi + 1);
    const float qx0 = x1 + sx * (float)(2 * pj);
    const float qx1 = x1 + sx * (float)(2 * pj + 1);

    int iy0; float wyA[2], wyB[3];
    axis_w(py0, py1, H_, iy0, wyA, wyB);
    int ix0; float wxA[2], wxB[3];
    axis_w(qx0, qx1, W_, ix0, wxA, wxB);

    const int b0 = iy0 * W_ + ix0;                   // <= 2499, fits 12 bits
    const int d1 = min(iy0 + 1, H_ - 1) - iy0;       // 0 or 1
    const int d2 = min(iy0 + 2, H_ - 1) - iy0;       // 0, 1 or 2
    const uint packed = (uint)b0 | ((uint)d1 << 12) | ((uint)d2 << 14);
    const uint oo = (uint)(ri * (C_ * PP_) + px);

    uint4* e = reinterpret_cast<uint4*>(tab) + (size_t)g * TBE_;
    e[0] = make_uint4(packed, oo, __float_as_uint(wyA[0]), __float_as_uint(wyA[1]));
    e[1] = make_uint4(__float_as_uint(wyB[0]), __float_as_uint(wyB[1]),
                      __float_as_uint(wyB[2]), __float_as_uint(wxA[0]));
    e[2] = make_uint4(__float_as_uint(wxA[1]), __float_as_uint(wxB[0]),
                      __float_as_uint(wxB[1]), __float_as_uint(wxB[2]));
}

// MAIN (r23 verbatim — best measured 67.7 us): channel-interleaved
// plane-resident LDS (stride 50, 40,032 B -> 4 blocks/CU with (512,8)),
// table-driven geometry (3 affine dwordx4 loads), 9 x ds_read_b128 gather,
// per-channel pruned reduce, 4 stores. r20 (2-task ILP) and r24 (table
// prefetch) both regressed via the VGPR/occupancy cliff -> this body is the
// fixed point of the explored design space.
__global__ __launch_bounds__(512, 8) void roipool_kernel(
    const uint* __restrict__ tab,
    const float* __restrict__ fm,
    float* __restrict__ out) {

    __shared__ float4 sh4[P4_];               // 40,032 B -> 4 blocks/CU

    const int b  = blockIdx.x;                // grid = N_ * 256
    const int n  = b >> 8;
    const int c0 = (b & 255) * CHB_;
    const int tid = threadIdx.x;
    const int lane = tid & 63;
    const int wv = __builtin_amdgcn_readfirstlane(tid >> 6);

    // ---- transpose-stage: thread p loads 4 coalesced dwords (one per plane,
    // stride HW_) and writes one aligned float4. p >= HW_ slots: clamped junk
    // (finite, never carries weight).
    {
        const int gpb = (n * C_ + c0) * HW_;
        for (int p = tid; p < P4_; p += 512) {
            const int sp = min(p, HW_ - 1);
            float4 v;
            v.x = fm[gpb + sp];
            v.y = fm[gpb + HW_ + sp];
            v.z = fm[gpb + 2 * HW_ + sp];
            v.w = fm[gpb + 3 * HW_ + sp];
            sh4[p] = v;
        }
    }
    __syncthreads();

    const size_t obase = ((size_t)n * R_ * C_ + c0) * PP_;
    const uint4* __restrict__ tb =
        reinterpret_cast<const uint4*>(tab) + (size_t)(n * NTASK + lane) * TBE_;

    for (int it = wv; it < NIT; it += WVS_) {
        const uint4* __restrict__ e = tb + (size_t)(it << 6) * TBE_;
        const uint4 E0 = e[0];
        const uint4 E1 = e[1];
        const uint4 E2 = e[2];

        const int b0 = (int)(E0.x & 0xFFFu);
        const int b1 = b0 + (int)((E0.x >> 12) & 3u) * W_;
        const int b2 = b0 + (int)((E0.x >> 14) & 3u) * W_;

        const float wyA0 = __uint_as_float(E0.z), wyA1 = __uint_as_float(E0.w);
        const float wyB0 = __uint_as_float(E1.x), wyB1 = __uint_as_float(E1.y);
        const float wyB2 = __uint_as_float(E1.z);
        const float wxA0 = __uint_as_float(E1.w), wxA1 = __uint_as_float(E2.x);
        const float wxB0 = __uint_as_float(E2.y), wxB1 = __uint_as_float(E2.z);
        const float wxB2 = __uint_as_float(E2.w);

        const float4* __restrict__ B0 = sh4 + b0;
        const float4* __restrict__ B1 = sh4 + b1;
        const float4* __restrict__ B2 = sh4 + b2;

        // 9 x ds_read_b128: the 3x3 window for all 4 channels at once.
        const float4 v00 = B0[0], v01 = B0[1], v02 = B0[2];
        const float4 v10 = B1[0], v11 = B1[1], v12 = B1[2];
        const float4 v20 = B2[0], v21 = B2[1], v22 = B2[2];

        float r0, r1, r2, r3;
#define REDUCE_CH(CMP, RES) do {                                               \
        const float tA0 = fmaf(wyA1, v10.CMP, wyA0 * v00.CMP);                 \
        const float tA1 = fmaf(wyA1, v11.CMP, wyA0 * v01.CMP);                 \
        const float tA2 = fmaf(wyA1, v12.CMP, wyA0 * v02.CMP);                 \
        const float tB0 = fmaf(wyB2, v20.CMP, fmaf(wyB1, v10.CMP, wyB0 * v00.CMP)); \
        const float tB1 = fmaf(wyB2, v21.CMP, fmaf(wyB1, v11.CMP, wyB0 * v01.CMP)); \
        const float tB2 = fmaf(wyB2, v22.CMP, fmaf(wyB1, v12.CMP, wyB0 * v02.CMP)); \
        const float s00 = fmaf(wxA1, tA1, wxA0 * tA0);                         \
        const float s01 = fmaf(wxB2, tA2, fmaf(wxB1, tA1, wxB0 * tA0));        \
        const float s10 = fmaf(wxA1, tB1, wxA0 * tB0);                         \
        const float s11 = fmaf(wxB2, tB2, fmaf(wxB1, tB1, wxB0 * tB0));        \
        RES = fmaxf(fmaxf(s00, s01), fmaxf(s10, s11));                         \
    } while (0)
        REDUCE_CH(x, r0);
        REDUCE_CH(y, r1);
        REDUCE_CH(z, r2);
        REDUCE_CH(w, r3);
#undef REDUCE_CH

        float* __restrict__ po = out + obase + E0.y;
        po[0]       = r0;
        po[PP_]     = r1;
        po[2 * PP_] = r2;
        po[3 * PP_] = r3;
    }
}

extern "C" void kernel_launch(void* const* d_in, const int* in_sizes, int n_in,
                              void* d_out, int out_size, void* d_ws, size_t ws_size,
                              hipStream_t stream) {
    const float* rois = (const float*)d_in[0];        // [4,256,4]
    const float* fm   = (const float*)d_in[1];        // [4,1024,50,50]
    float* out        = (float*)d_out;                // [4,256,1024,7,7]
    uint* tab         = (uint*)d_ws;                  // 50176 * 48 B = 2.41 MB

    geom_kernel<<<196, 256, 0, stream>>>(rois, tab);
    const int blocks = N_ * (C_ / CHB_);              // 4 * 256 = 1024
    roipool_kernel<<<blocks, 512, 0, stream>>>(tab, fm, out);
}